// Round 7
// baseline (285.826 us; speedup 1.0000x reference)
//
#include <hip/hip_runtime.h>
#include <stdint.h>

typedef unsigned short u16;
typedef __attribute__((ext_vector_type(8))) __bf16 bf16x8;
typedef __attribute__((ext_vector_type(4))) float f32x4;

#define AS1 __attribute__((address_space(1)))
#define AS3 __attribute__((address_space(3)))
#define LOG2E 1.4426950408889634f

#define BAR() __builtin_amdgcn_s_barrier()
#define VMC6() asm volatile("s_waitcnt vmcnt(6)" ::: "memory")
#define VMC0() asm volatile("s_waitcnt vmcnt(0)" ::: "memory")

__device__ __forceinline__ u16 f2bf(float f) {
    union { __bf16 h; u16 u; } cv;
    cv.h = (__bf16)f;   // native cvt (RTNE)
    return cv.u;
}

__device__ __forceinline__ float vmax4(f32x4 x) {
    return fmaxf(fmaxf(x[0], x[1]), fmaxf(x[2], x[3]));
}
__device__ __forceinline__ float vsum4(f32x4 x) {
    return (x[0] + x[1]) + (x[2] + x[3]);
}

// ---------------------------------------------------------------------------
// fp32 -> bf16 convert, 8 elements/thread.
// ---------------------------------------------------------------------------
__global__ __launch_bounds__(256) void cvt_kernel(
    const float* __restrict__ src, u16* __restrict__ dst, int n8)
{
    int i = blockIdx.x * 256 + threadIdx.x;
    if (i >= n8) return;
    const float4* s = (const float4*)src;
    float4 f0 = s[(size_t)i * 2], f1 = s[(size_t)i * 2 + 1];
    ushort4 a, b;
    a.x = f2bf(f0.x); a.y = f2bf(f0.y); a.z = f2bf(f0.z); a.w = f2bf(f0.w);
    b.x = f2bf(f1.x); b.y = f2bf(f1.y); b.z = f2bf(f1.z); b.w = f2bf(f1.w);
    ((ushort4*)dst)[(size_t)i * 2]     = a;
    ((ushort4*)dst)[(size_t)i * 2 + 1] = b;
}

// Wq|Wk|Wv in one launch; Wq gets the 1/8 attention scale folded in.
__global__ __launch_bounds__(256) void cvt3_kernel(
    const float* __restrict__ wq, const float* __restrict__ wk,
    const float* __restrict__ wv, u16* __restrict__ dst)
{
    int i = blockIdx.x * 256 + threadIdx.x;
    int seg = i >> 17;
    const float* s = (seg == 0) ? wq : (seg == 1) ? wk : wv;
    float sc = (seg == 0) ? 0.125f : 1.0f;
    int j = i & 131071;
    const float4* sp = (const float4*)s;
    float4 f0 = sp[(size_t)j * 2], f1 = sp[(size_t)j * 2 + 1];
    ushort4 a, b;
    a.x = f2bf(f0.x * sc); a.y = f2bf(f0.y * sc); a.z = f2bf(f0.z * sc); a.w = f2bf(f0.w * sc);
    b.x = f2bf(f1.x * sc); b.y = f2bf(f1.y * sc); b.z = f2bf(f1.z * sc); b.w = f2bf(f1.w * sc);
    ((ushort4*)dst)[(size_t)i * 2]     = a;
    ((ushort4*)dst)[(size_t)i * 2 + 1] = b;
}

// ---------------------------------------------------------------------------
// 256x256 / BK=64 8-phase GEMM (QKV). R7: LDS-staged coalesced epilogue.
// ---------------------------------------------------------------------------
#define LDS_OFF(p, h) ((((p) * 4 + (h)) * 8192))

__device__ __forceinline__ void stage_A(
    const u16* __restrict__ G, int kt, int hm, u16* region, int t)
{
    int w6 = t & ~63;
#pragma unroll
    for (int i = 0; i < 2; ++i) {
        int s = i * 512 + t;
        int r = s >> 3;
        int j = (s & 7) ^ (r & 7);
        int row = (r & 63) + ((r >> 6) << 7) + (hm << 6);   // mh-interleaved
        const u16* g = G + (size_t)row * 1024 + kt * 64 + j * 8;
        u16* lp = region + (i * 512 + w6) * 8;              // wave-uniform base
        __builtin_amdgcn_global_load_lds((AS1 unsigned int*)g, (AS3 unsigned int*)lp, 16, 0, 0);
    }
}

__device__ __forceinline__ void stage_B(
    const u16* __restrict__ G, int kt, int hb, u16* region, int t)
{
    int w6 = t & ~63;
#pragma unroll
    for (int i = 0; i < 2; ++i) {
        int s = i * 512 + t;
        int r = s >> 3;
        int j = (s & 7) ^ (r & 7);
        int row = hb * 128 + r;
        const u16* g = G + (size_t)row * 1024 + kt * 64 + j * 8;
        u16* lp = region + (i * 512 + w6) * 8;
        __builtin_amdgcn_global_load_lds((AS1 unsigned int*)g, (AS3 unsigned int*)lp, 16, 0, 0);
    }
}

__device__ __forceinline__ bf16x8 fragr(const u16* region, int row, int j) {
    int byte = row * 128 + ((j ^ (row & 7)) << 4);
    return *(const bf16x8*)((const char*)region + byte);
}

__global__ __launch_bounds__(512, 2) void gemm_qkv_256(
    const u16* __restrict__ X, const u16* __restrict__ W3, u16* __restrict__ QKV)
{
    __shared__ __attribute__((aligned(16))) u16 lds[65536];   // 128 KB

    const int t  = threadIdx.x;
    const int l  = t & 63, w = t >> 6;
    const int wm = w >> 2, wn = w & 3;
    const int lr = l & 15, lg = l >> 4;

    // bijective XCD chunking: nwg=384=8*48
    int bid = (int)blockIdx.x;
    int wg  = (bid & 7) * 48 + (bid >> 3);
    int mx  = wg / 12, ny = wg % 12;
    const int mb = mx * 256, nb = ny * 256;
    const u16* A = X  + (size_t)mb * 1024;
    const u16* B = W3 + (size_t)nb * 1024;

    const int NT = 16;   // K=1024 / BK=64

    stage_A(A, 0, 0, lds + LDS_OFF(0, 0), t);
    stage_B(B, 0, 0, lds + LDS_OFF(0, 2), t);
    stage_B(B, 0, 1, lds + LDS_OFF(0, 3), t);
    stage_A(A, 0, 1, lds + LDS_OFF(0, 1), t);
    stage_A(A, 1, 0, lds + LDS_OFF(1, 0), t);
    stage_B(B, 1, 0, lds + LDS_OFF(1, 2), t);
    stage_B(B, 1, 1, lds + LDS_OFF(1, 3), t);
    VMC6();
    BAR();

    f32x4 acc[8][4];
#pragma unroll
    for (int i = 0; i < 8; ++i)
#pragma unroll
        for (int j = 0; j < 4; ++j) acc[i][j] = f32x4{0.f, 0.f, 0.f, 0.f};

    for (int kt = 0; kt < NT; ++kt) {
        const int p = kt & 1;
        u16* A0r = lds + LDS_OFF(p, 0);
        u16* A1r = lds + LDS_OFF(p, 1);
        u16* B0r = lds + LDS_OFF(p, 2);
        u16* B1r = lds + LDS_OFF(p, 3);
        u16* A1n = lds + LDS_OFF(p ^ 1, 1);
        const u16* Bw = (wn >= 2) ? B1r : B0r;
        const int brow0 = (wn & 1) * 64;

        bf16x8 af[4][2], bf[4][2];

        // ph1
#pragma unroll
        for (int mi = 0; mi < 4; ++mi)
#pragma unroll
            for (int ks = 0; ks < 2; ++ks)
                af[mi][ks] = fragr(A0r, wm * 64 + mi * 16 + lr, ks * 4 + lg);
#pragma unroll
        for (int ni = 0; ni < 2; ++ni)
#pragma unroll
            for (int ks = 0; ks < 2; ++ks)
                bf[ni][ks] = fragr(Bw, brow0 + ni * 16 + lr, ks * 4 + lg);
        if (kt + 1 < NT) stage_A(A, kt + 1, 1, A1n, t);
        BAR();
        __builtin_amdgcn_s_setprio(1);
#pragma unroll
        for (int mi = 0; mi < 4; ++mi)
#pragma unroll
            for (int ni = 0; ni < 2; ++ni)
#pragma unroll
                for (int ks = 0; ks < 2; ++ks)
                    acc[mi][ni] = __builtin_amdgcn_mfma_f32_16x16x32_bf16(af[mi][ks], bf[ni][ks], acc[mi][ni], 0, 0, 0);
        __builtin_amdgcn_s_setprio(0);
        BAR();

        // ph2
#pragma unroll
        for (int ni = 2; ni < 4; ++ni)
#pragma unroll
            for (int ks = 0; ks < 2; ++ks)
                bf[ni][ks] = fragr(Bw, brow0 + ni * 16 + lr, ks * 4 + lg);
        if (kt + 2 < NT) stage_A(A, kt + 2, 0, A0r, t);
        BAR();
        __builtin_amdgcn_s_setprio(1);
#pragma unroll
        for (int mi = 0; mi < 4; ++mi)
#pragma unroll
            for (int ni = 2; ni < 4; ++ni)
#pragma unroll
                for (int ks = 0; ks < 2; ++ks)
                    acc[mi][ni] = __builtin_amdgcn_mfma_f32_16x16x32_bf16(af[mi][ks], bf[ni][ks], acc[mi][ni], 0, 0, 0);
        __builtin_amdgcn_s_setprio(0);
        BAR();

        // ph3
#pragma unroll
        for (int mi = 0; mi < 4; ++mi)
#pragma unroll
            for (int ks = 0; ks < 2; ++ks)
                af[mi][ks] = fragr(A1r, wm * 64 + mi * 16 + lr, ks * 4 + lg);
        if (kt + 2 < NT) stage_B(B, kt + 2, 0, B0r, t);
        BAR();
        __builtin_amdgcn_s_setprio(1);
#pragma unroll
        for (int mi = 0; mi < 4; ++mi)
#pragma unroll
            for (int ni = 0; ni < 2; ++ni)
#pragma unroll
                for (int ks = 0; ks < 2; ++ks)
                    acc[4 + mi][ni] = __builtin_amdgcn_mfma_f32_16x16x32_bf16(af[mi][ks], bf[ni][ks], acc[4 + mi][ni], 0, 0, 0);
        __builtin_amdgcn_s_setprio(0);
        BAR();

        // ph4
        if (kt + 2 < NT) {
            stage_B(B, kt + 2, 1, B1r, t);
            VMC6();
        } else if (kt + 1 < NT) {
            VMC0();
        }
        BAR();
        __builtin_amdgcn_s_setprio(1);
#pragma unroll
        for (int mi = 0; mi < 4; ++mi)
#pragma unroll
            for (int ni = 2; ni < 4; ++ni)
#pragma unroll
                for (int ks = 0; ks < 2; ++ks)
                    acc[4 + mi][ni] = __builtin_amdgcn_mfma_f32_16x16x32_bf16(af[mi][ks], bf[ni][ks], acc[4 + mi][ni], 0, 0, 0);
        __builtin_amdgcn_s_setprio(0);
        BAR();
    }

    // ---- epilogue: LDS-staged coalesced stores (stride 264 u16 = bank-spread)
    u16* ep = lds;
#pragma unroll
    for (int mi = 0; mi < 8; ++mi) {
#pragma unroll
        for (int ni = 0; ni < 4; ++ni)
#pragma unroll
            for (int v = 0; v < 4; ++v)
                ep[(wm * 16 + lg * 4 + v) * 264 + wn * 64 + ni * 16 + lr] = f2bf(acc[mi][ni][v]);
        BAR();
#pragma unroll
        for (int c = 0; c < 2; ++c) {
            int ch = c * 512 + t;
            int srow = ch >> 5, col8 = (ch & 31) << 3;
            int grow = mb + ((srow >> 4) << 7) + mi * 16 + (srow & 15);
            *(uint4*)(QKV + (size_t)grow * 3072 + nb + col8) =
                *(const uint4*)(ep + srow * 264 + col8);
        }
        BAR();
    }
}

// ---------------------------------------------------------------------------
// m97-style 128x128 GEMM (output projection). R7: coalesced f32 epilogue.
// ---------------------------------------------------------------------------
__device__ __forceinline__ void gemm_tile_body_f32(
    const u16* __restrict__ A, const u16* __restrict__ B, float* __restrict__ Cp,
    int K, int ldc, int mb, int nb, u16* sh)
{
    u16* As = sh;
    u16* Bs = sh + 128 * 32;

    const int t  = threadIdx.x;
    const int l  = t & 63, w = t >> 6;
    const int wm = w >> 1, wn = w & 1;
    const int lr = l & 15, lg = l >> 4;

    f32x4 acc[4][4];
#pragma unroll
    for (int i = 0; i < 4; ++i)
#pragma unroll
        for (int j = 0; j < 4; ++j) acc[i][j] = f32x4{0.f, 0.f, 0.f, 0.f};

    for (int k0 = 0; k0 < K; k0 += 32) {
        __syncthreads();
#pragma unroll
        for (int i = 0; i < 2; ++i) {
            int chunk = i * 256 + t;
            int row   = chunk >> 2;
            int c8    = (chunk & 3) << 3;
            const u16* ga = A + (size_t)(mb + row) * K + k0 + c8;
            const u16* gb = B + (size_t)(nb + row) * K + k0 + c8;
            u16* la = As + (i * 256 + w * 64) * 8;
            u16* lb = Bs + (i * 256 + w * 64) * 8;
            __builtin_amdgcn_global_load_lds((AS1 unsigned int*)ga, (AS3 unsigned int*)la, 16, 0, 0);
            __builtin_amdgcn_global_load_lds((AS1 unsigned int*)gb, (AS3 unsigned int*)lb, 16, 0, 0);
        }
        __syncthreads();
        bf16x8 af[4], bfr[4];
#pragma unroll
        for (int mi = 0; mi < 4; ++mi)
            af[mi] = *(const bf16x8*)(As + (wm * 64 + mi * 16 + lr) * 32 + lg * 8);
#pragma unroll
        for (int ni = 0; ni < 4; ++ni)
            bfr[ni] = *(const bf16x8*)(Bs + (wn * 64 + ni * 16 + lr) * 32 + lg * 8);
#pragma unroll
        for (int mi = 0; mi < 4; ++mi)
#pragma unroll
            for (int ni = 0; ni < 4; ++ni)
                acc[mi][ni] = __builtin_amdgcn_mfma_f32_16x16x32_bf16(af[mi], bfr[ni], acc[mi][ni], 0, 0, 0);
    }

    // ---- epilogue: LDS-staged float4 stores (stride 132 f32 = bank-spread)
    __syncthreads();
    float* epf = (float*)sh;
#pragma unroll
    for (int s = 0; s < 8; ++s) {
        int wmS = s >> 2, miS = s & 3;
        if (wm == wmS) {
#pragma unroll
            for (int ni = 0; ni < 4; ++ni)
#pragma unroll
                for (int v = 0; v < 4; ++v)
                    epf[(lg * 4 + v) * 132 + wn * 64 + ni * 16 + lr] = acc[miS][ni][v];
        }
        __syncthreads();
#pragma unroll
        for (int c = 0; c < 2; ++c) {
            int ch = c * 256 + t;
            int srow = ch >> 5, c4 = (ch & 31) << 2;
            *(float4*)(Cp + (size_t)(mb + wmS * 64 + miS * 16 + srow) * ldc + nb + c4) =
                *(const float4*)(epf + srow * 132 + c4);
        }
        __syncthreads();
    }
}

__global__ __launch_bounds__(256, 2) void gemm_out_kernel(
    const u16* __restrict__ A, const u16* __restrict__ B, float* __restrict__ C)
{
    __shared__ __attribute__((aligned(16))) u16 sh[128 * 32 * 2];  // 16 KB
    int bid = (int)blockIdx.x + (int)gridDim.x * (int)blockIdx.y;  // nwg=512
    int wg  = (bid & 7) * 64 + (bid >> 3);
    int mx  = wg >> 3;
    int my  = wg & 7;
    gemm_tile_body_f32(A, B, C, 1024, 1024, mx * 128, my * 128, sh);
}

// ---------------------------------------------------------------------------
// Causal flash attention (swapped-operand MFMA). R7: double-buffered K/V LDS,
// ONE barrier per k-tile; commit overlapped with compute.
// ---------------------------------------------------------------------------
#define SEQ  2048
#define PSTR 72
#define NQT  16

__device__ __forceinline__ void kv_commit(
    u16* KD, u16* VD, const uint4* kpf, const uint4* vpf, int sr, int sc)
{
#pragma unroll
    for (int i = 0; i < 2; ++i) {
        int r = sr + i * 32;
        *(uint4*)(KD + r * PSTR + sc) = kpf[i];
        int rs = r ^ sc;                    // Vt transpose-store swizzle
        union { uint4 q; u16 u[8]; } uv; uv.q = vpf[i];
#pragma unroll
        for (int j = 0; j < 8; ++j)
            VD[(sc + j) * PSTR + rs] = uv.u[j];
    }
}

__device__ __forceinline__ void kv_prefetch(
    uint4* kpf, uint4* vpf, const u16* Kg, const u16* Vg, int k0, int sr, int sc)
{
#pragma unroll
    for (int i = 0; i < 2; ++i) {
        int r = k0 + sr + i * 32;
        kpf[i] = *(const uint4*)(Kg + (size_t)r * 3072 + sc);
        vpf[i] = *(const uint4*)(Vg + (size_t)r * 3072 + sc);
    }
}

__device__ __forceinline__ void attn_qtile(
    const u16* __restrict__ Qg, const u16* __restrict__ Kg, const u16* __restrict__ Vg,
    u16* __restrict__ outp, int b, int h, int qt,
    u16* QP, u16* Ks0, u16* Ks1, u16* Vt0, u16* Vt1)
{
    const int t  = threadIdx.x;
    const int l  = t & 63, w = t >> 6;
    const int lr = l & 15, lg = l >> 4;
    const int q0 = qt * 128;
    const int sr = t >> 3;
    const int sc = (t & 7) << 3;

    // ---- stage Q, extract per-wave fragments ----
    __syncthreads();                 // prev q-tile's users of QP/Ks/Vt done
#pragma unroll
    for (int i = 0; i < 4; ++i) {
        int r = sr + i * 32;
        *(uint4*)(QP + r * PSTR + sc) = *(const uint4*)(Qg + (size_t)(q0 + r) * 3072 + sc);
    }
    __syncthreads();
    bf16x8 qf[2][2];
#pragma unroll
    for (int mi = 0; mi < 2; ++mi)
#pragma unroll
        for (int ks = 0; ks < 2; ++ks)
            qf[mi][ks] = *(const bf16x8*)(QP + (w * 32 + mi * 16 + lr) * PSTR + ks * 32 + lg * 8);

    const int nkt = 2 * qt + 2;
    uint4 kpf[2], vpf[2];
    kv_prefetch(kpf, vpf, Kg, Vg, 0, sr, sc);
    kv_commit(Ks0, Vt0, kpf, vpf, sr, sc);       // tile 0 -> buf0
    if (nkt > 1) kv_prefetch(kpf, vpf, Kg, Vg, 64, sr, sc);
    __syncthreads();                 // buf0 visible to all

    f32x4 o[4][2];
#pragma unroll
    for (int nd = 0; nd < 4; ++nd)
#pragma unroll
        for (int mi = 0; mi < 2; ++mi) o[nd][mi] = f32x4{0.f, 0.f, 0.f, 0.f};
    float mrow[2]  = { -__builtin_inff(), -__builtin_inff() };
    float mrowL[2] = { -__builtin_inff(), -__builtin_inff() };
    float lrow[2]  = { 0.f, 0.f };

    for (int kt = 0; kt < nkt; ++kt) {
        const int k0 = kt * 64;
        u16* Ksc = (kt & 1) ? Ks1 : Ks0;
        u16* Vtc = (kt & 1) ? Vt1 : Vt0;
        u16* Ksn = (kt & 1) ? Ks0 : Ks1;
        u16* Vtn = (kt & 1) ? Vt0 : Vt1;

        // ---- commit next tile (other buffer), prefetch tile kt+2 ----
        if (kt + 1 < nkt) {
            kv_commit(Ksn, Vtn, kpf, vpf, sr, sc);
            if (kt + 2 < nkt) kv_prefetch(kpf, vpf, Kg, Vg, k0 + 128, sr, sc);
        }

        // ---- QK^T (swapped: A=K, B=Q) ----
        f32x4 s[4][2];
#pragma unroll
        for (int ni = 0; ni < 4; ++ni)
#pragma unroll
            for (int mi = 0; mi < 2; ++mi) s[ni][mi] = f32x4{0.f, 0.f, 0.f, 0.f};
        __builtin_amdgcn_s_setprio(1);
#pragma unroll
        for (int ks = 0; ks < 2; ++ks) {
            bf16x8 kb[4];
#pragma unroll
            for (int ni = 0; ni < 4; ++ni)
                kb[ni] = *(const bf16x8*)(Ksc + (ni * 16 + lr) * PSTR + ks * 32 + lg * 8);
#pragma unroll
            for (int ni = 0; ni < 4; ++ni)
#pragma unroll
                for (int mi = 0; mi < 2; ++mi)
                    s[ni][mi] = __builtin_amdgcn_mfma_f32_16x16x32_bf16(kb[ni], qf[mi][ks], s[ni][mi], 0, 0, 0);
        }
        __builtin_amdgcn_s_setprio(0);

        // ---- causal mask (diagonal waves only; qpos lane-local) ----
#pragma unroll
        for (int mi = 0; mi < 2; ++mi) {
            if ((k0 + 63) > (q0 + w * 32 + mi * 16)) {
                int qpos = q0 + w * 32 + mi * 16 + lr;
#pragma unroll
                for (int ni = 0; ni < 4; ++ni) {
                    int kb0 = k0 + ni * 16 + lg * 4;
#pragma unroll
                    for (int v = 0; v < 4; ++v)
                        if (kb0 + v > qpos) s[ni][mi][v] = -__builtin_inff();
                }
            }
        }

        // ---- online softmax (exp2 domain, bit-exact defer-rescale) ----
        float rmax[2];
        bool grew = false;
#pragma unroll
        for (int mi = 0; mi < 2; ++mi) {
            float r = fmaxf(fmaxf(vmax4(s[0][mi]), vmax4(s[1][mi])),
                            fmaxf(vmax4(s[2][mi]), vmax4(s[3][mi])));
            r = fmaxf(r, __shfl_xor(r, 16));
            r = fmaxf(r, __shfl_xor(r, 32));
            rmax[mi] = r;
            grew |= (r > mrow[mi]);
        }
        if (__ballot(grew)) {
#pragma unroll
            for (int mi = 0; mi < 2; ++mi) {
                float mn  = fmaxf(mrow[mi], rmax[mi]);
                float mnL = mn * LOG2E;
                float al  = __builtin_amdgcn_exp2f(mrowL[mi] - mnL);
                mrow[mi]  = mn;
                mrowL[mi] = mnL;
                lrow[mi] *= al;
#pragma unroll
                for (int nd = 0; nd < 4; ++nd)
#pragma unroll
                    for (int v = 0; v < 4; ++v) o[nd][mi][v] *= al;
            }
        }
#pragma unroll
        for (int mi = 0; mi < 2; ++mi) {
            float nmL = -mrowL[mi];
#pragma unroll
            for (int ni = 0; ni < 4; ++ni)
#pragma unroll
                for (int v = 0; v < 4; ++v)
                    s[ni][mi][v] = __builtin_amdgcn_exp2f(
                        __builtin_fmaf(s[ni][mi][v], LOG2E, nmL));
            float sum = (vsum4(s[0][mi]) + vsum4(s[1][mi]))
                      + (vsum4(s[2][mi]) + vsum4(s[3][mi]));
            sum += __shfl_xor(sum, 16);
            sum += __shfl_xor(sum, 32);
            lrow[mi] += sum;
            int prow = (w * 32 + mi * 16 + lr) * PSTR + lg * 4;
#pragma unroll
            for (int ni = 0; ni < 4; ++ni) {
                ushort4 u;
                u.x = f2bf(s[ni][mi][0]); u.y = f2bf(s[ni][mi][1]);
                u.z = f2bf(s[ni][mi][2]); u.w = f2bf(s[ni][mi][3]);
                *(ushort4*)(QP + prow + ni * 16) = u;
            }
        }

        // ---- PV (swapped: A=V', B=P) ----
        __builtin_amdgcn_s_setprio(1);
#pragma unroll
        for (int ks = 0; ks < 2; ++ks) {
            bf16x8 pa[2], vb[4];
#pragma unroll
            for (int mi = 0; mi < 2; ++mi)
                pa[mi] = *(const bf16x8*)(QP + (w * 32 + mi * 16 + lr) * PSTR + ks * 32 + lg * 8);
#pragma unroll
            for (int nd = 0; nd < 4; ++nd) {
                int d = nd * 16 + lr;
                vb[nd] = *(const bf16x8*)(Vtc + d * PSTR + ((ks * 32 + lg * 8) ^ (((d >> 3) & 7) << 3)));
            }
#pragma unroll
            for (int nd = 0; nd < 4; ++nd)
#pragma unroll
                for (int mi = 0; mi < 2; ++mi)
                    o[nd][mi] = __builtin_amdgcn_mfma_f32_16x16x32_bf16(vb[nd], pa[mi], o[nd][mi], 0, 0, 0);
        }
        __builtin_amdgcn_s_setprio(0);

        __syncthreads();   // single barrier: cur^1 commit visible; cur reads done
    }

    // ---- epilogue ----
#pragma unroll
    for (int mi = 0; mi < 2; ++mi) {
        float inv = 1.f / lrow[mi];
        int row = q0 + w * 32 + mi * 16 + lr;
        u16* op = outp + (size_t)(b * SEQ + row) * 1024 + h * 64 + lg * 4;
#pragma unroll
        for (int nd = 0; nd < 4; ++nd) {
            ushort4 u;
            u.x = f2bf(o[nd][mi][0] * inv); u.y = f2bf(o[nd][mi][1] * inv);
            u.z = f2bf(o[nd][mi][2] * inv); u.w = f2bf(o[nd][mi][3] * inv);
            *(ushort4*)(op + nd * 16) = u;
        }
    }
}

__global__ __launch_bounds__(256, 2) void attn_kernel(
    const u16* __restrict__ qkv, u16* __restrict__ outp)
{
    __shared__ __attribute__((aligned(16))) u16 QP[128 * PSTR];
    __shared__ __attribute__((aligned(16))) u16 Ks0[64 * PSTR];
    __shared__ __attribute__((aligned(16))) u16 Ks1[64 * PSTR];
    __shared__ __attribute__((aligned(16))) u16 Vt0[64 * PSTR];
    __shared__ __attribute__((aligned(16))) u16 Vt1[64 * PSTR];

    const int bid = (int)blockIdx.x + (int)blockIdx.y * 8;
    const int xcd = bid & 7;
    const int j   = bid >> 3;
    const int bh  = xcd * 8 + (j & 7);
    const int qp  = j >> 3;
    const int b   = bh >> 4, h = bh & 15;

    const u16* Qg = qkv + (size_t)b * SEQ * 3072 + h * 64;
    const u16* Kg = Qg + 1024;
    const u16* Vg = Qg + 2048;

    attn_qtile(Qg, Kg, Vg, outp, b, h, qp,           QP, Ks0, Ks1, Vt0, Vt1);
    attn_qtile(Qg, Kg, Vg, outp, b, h, NQT - 1 - qp, QP, Ks0, Ks1, Vt0, Vt1);
}

// ---------------------------------------------------------------------------
extern "C" void kernel_launch(void* const* d_in, const int* in_sizes, int n_in,
                              void* d_out, int out_size, void* d_ws, size_t ws_size,
                              hipStream_t stream)
{
    (void)in_sizes; (void)n_in; (void)out_size; (void)ws_size;
    const float* x  = (const float*)d_in[0];
    const float* Wq = (const float*)d_in[1];
    const float* Wk = (const float*)d_in[2];
    const float* Wv = (const float*)d_in[3];
    const float* Wo = (const float*)d_in[4];

    u16*   qkv = (u16*)d_ws;                     // [8192,3072] bf16
    u16*   xb  = qkv + (size_t)8192 * 3072;      // [8192,1024] bf16
    u16*   att = xb;                             // alias: xb dead after QKV GEMM
    u16*   w3  = (u16*)d_out;                    // Wq|Wk|Wv bf16 scratch
    u16*   wob = qkv;                            // Wo bf16 -> dead qkv region
    float* out = (float*)d_out;                  // final [8192,1024] fp32

    cvt_kernel <<<dim3(4096), 256, 0, stream>>>(x, xb, 1048576);
    cvt3_kernel<<<dim3(1536), 256, 0, stream>>>(Wq, Wk, Wv, w3);  // Wq pre-scaled 1/8

    gemm_qkv_256<<<dim3(384), 512, 0, stream>>>(xb, w3, qkv);
    attn_kernel <<<dim3(8, 64), 256, 0, stream>>>(qkv, att);

    cvt_kernel<<<dim3(512), 256, 0, stream>>>(Wo, wob, 131072);
    gemm_out_kernel<<<dim3(64, 8), 256, 0, stream>>>(att, wob, out);
}

// Round 8
// 272.502 us; speedup vs baseline: 1.0489x; 1.0489x over previous
//
#include <hip/hip_runtime.h>
#include <stdint.h>

typedef unsigned short u16;
typedef __attribute__((ext_vector_type(8))) __bf16 bf16x8;
typedef __attribute__((ext_vector_type(4))) float f32x4;

#define AS1 __attribute__((address_space(1)))
#define AS3 __attribute__((address_space(3)))
#define LOG2E 1.4426950408889634f

#define BAR() __builtin_amdgcn_s_barrier()
#define VMC5() asm volatile("s_waitcnt vmcnt(5)" ::: "memory")
#define VMC0() asm volatile("s_waitcnt vmcnt(0)" ::: "memory")

__device__ __forceinline__ u16 f2bf(float f) {
    union { __bf16 h; u16 u; } cv;
    cv.h = (__bf16)f;   // native cvt (RTNE)
    return cv.u;
}

__device__ __forceinline__ float vmax4(f32x4 x) {
    return fmaxf(fmaxf(x[0], x[1]), fmaxf(x[2], x[3]));
}
__device__ __forceinline__ float vsum4(f32x4 x) {
    return (x[0] + x[1]) + (x[2] + x[3]);
}

// ---------------------------------------------------------------------------
// fp32 -> bf16 convert, 8 elements/thread.
// ---------------------------------------------------------------------------
__global__ __launch_bounds__(256) void cvt_kernel(
    const float* __restrict__ src, u16* __restrict__ dst, int n8)
{
    int i = blockIdx.x * 256 + threadIdx.x;
    if (i >= n8) return;
    const float4* s = (const float4*)src;
    float4 f0 = s[(size_t)i * 2], f1 = s[(size_t)i * 2 + 1];
    ushort4 a, b;
    a.x = f2bf(f0.x); a.y = f2bf(f0.y); a.z = f2bf(f0.z); a.w = f2bf(f0.w);
    b.x = f2bf(f1.x); b.y = f2bf(f1.y); b.z = f2bf(f1.z); b.w = f2bf(f1.w);
    ((ushort4*)dst)[(size_t)i * 2]     = a;
    ((ushort4*)dst)[(size_t)i * 2 + 1] = b;
}

// Wq|Wk|Wv in one launch; Wq gets the 1/8 attention scale folded in.
__global__ __launch_bounds__(256) void cvt3_kernel(
    const float* __restrict__ wq, const float* __restrict__ wk,
    const float* __restrict__ wv, u16* __restrict__ dst)
{
    int i = blockIdx.x * 256 + threadIdx.x;
    int seg = i >> 17;
    const float* s = (seg == 0) ? wq : (seg == 1) ? wk : wv;
    float sc = (seg == 0) ? 0.125f : 1.0f;
    int j = i & 131071;
    const float4* sp = (const float4*)s;
    float4 f0 = sp[(size_t)j * 2], f1 = sp[(size_t)j * 2 + 1];
    ushort4 a, b;
    a.x = f2bf(f0.x * sc); a.y = f2bf(f0.y * sc); a.z = f2bf(f0.z * sc); a.w = f2bf(f0.w * sc);
    b.x = f2bf(f1.x * sc); b.y = f2bf(f1.y * sc); b.z = f2bf(f1.z * sc); b.w = f2bf(f1.w * sc);
    ((ushort4*)dst)[(size_t)i * 2]     = a;
    ((ushort4*)dst)[(size_t)i * 2 + 1] = b;
}

// ---------------------------------------------------------------------------
// 256x192 / BK=64 4-phase GEMM (QKV): grid 32x16 = 512 blocks = 2 CLEAN
// ROUNDS on 256 CUs (R8: was 384 = 1.5 rounds = 75% util).
// 512 threads (8 waves 2Mx4N); per-wave 128x48; LDS 112 KB 2-dbuf;
// G4 swizzle byte^=(row&7)<<4 both sides; counted vmcnt(5), never 0 in loop.
// Per buffer: A0[128x64] | A1[128x64] | B[192x64]  (A mh-interleaved).
// ---------------------------------------------------------------------------
#define QBUF 28672   // u16 per buffer

__device__ __forceinline__ void stage_A(
    const u16* __restrict__ G, int kt, int hm, u16* region, int t)
{
    int w6 = t & ~63;
#pragma unroll
    for (int i = 0; i < 2; ++i) {
        int s = i * 512 + t;
        int r = s >> 3;
        int j = (s & 7) ^ (r & 7);
        int row = (r & 63) + ((r >> 6) << 7) + (hm << 6);   // mh-interleaved
        const u16* g = G + (size_t)row * 1024 + kt * 64 + j * 8;
        u16* lp = region + (i * 512 + w6) * 8;              // wave-uniform base
        __builtin_amdgcn_global_load_lds((AS1 unsigned int*)g, (AS3 unsigned int*)lp, 16, 0, 0);
    }
}

// B rows 0-127 (2 loads/thread)
__device__ __forceinline__ void stage_B01(
    const u16* __restrict__ G, int kt, u16* region, int t)
{
    int w6 = t & ~63;
#pragma unroll
    for (int i = 0; i < 2; ++i) {
        int s = i * 512 + t;
        int r = s >> 3;
        int j = (s & 7) ^ (r & 7);
        const u16* g = G + (size_t)r * 1024 + kt * 64 + j * 8;
        u16* lp = region + (i * 512 + w6) * 8;
        __builtin_amdgcn_global_load_lds((AS1 unsigned int*)g, (AS3 unsigned int*)lp, 16, 0, 0);
    }
}

// B rows 128-191 (1 load/thread)
__device__ __forceinline__ void stage_B2(
    const u16* __restrict__ G, int kt, u16* region, int t)
{
    int r = t >> 3;
    int j = (t & 7) ^ (r & 7);
    const u16* g = G + (size_t)(128 + r) * 1024 + kt * 64 + j * 8;
    u16* lp = region + 8192 + ((t & ~63)) * 8;
    __builtin_amdgcn_global_load_lds((AS1 unsigned int*)g, (AS3 unsigned int*)lp, 16, 0, 0);
}

__device__ __forceinline__ bf16x8 fragr(const u16* region, int row, int j) {
    int byte = row * 128 + ((j ^ (row & 7)) << 4);
    return *(const bf16x8*)((const char*)region + byte);
}

__global__ __launch_bounds__(512, 2) void gemm_qkv_256(
    const u16* __restrict__ X, const u16* __restrict__ W3, u16* __restrict__ QKV)
{
    __shared__ __attribute__((aligned(16))) u16 lds[57344];   // 112 KB

    const int t  = threadIdx.x;
    const int l  = t & 63, w = t >> 6;
    const int wm = w >> 2, wn = w & 3;
    const int lr = l & 15, lg = l >> 4;

    // bijective XCD chunking: nwg=512=8*64
    int bid = (int)blockIdx.x;
    int wg  = (bid & 7) * 64 + (bid >> 3);
    int mx  = wg >> 4, ny = wg & 15;
    const int mb = mx * 256, nb = ny * 192;
    const u16* A = X  + (size_t)mb * 1024;
    const u16* B = W3 + (size_t)nb * 1024;

    const int NT = 16;   // K=1024 / BK=64

    // prologue: tile0 = 7 loads, tile1 partial = 5 -> VMC5 lands tile0
    stage_A  (A, 0, 0, lds + 0,             t);
    stage_B01(B, 0,    lds + 16384,         t);
    stage_B2 (B, 0,    lds + 16384,         t);
    stage_A  (A, 0, 1, lds + 8192,          t);
    stage_A  (A, 1, 0, lds + QBUF + 0,      t);
    stage_B01(B, 1,    lds + QBUF + 16384,  t);
    stage_B2 (B, 1,    lds + QBUF + 16384,  t);
    VMC5();
    BAR();

    f32x4 acc[8][3];
#pragma unroll
    for (int i = 0; i < 8; ++i)
#pragma unroll
        for (int j = 0; j < 3; ++j) acc[i][j] = f32x4{0.f, 0.f, 0.f, 0.f};

    const int brow0 = wn * 48;

    for (int kt = 0; kt < NT; ++kt) {
        const int p = kt & 1;
        u16* A0r = lds + p * QBUF;
        u16* A1r = A0r + 8192;
        u16* Br  = A0r + 16384;
        u16* A1n = lds + (p ^ 1) * QBUF + 8192;
        u16* Bn  = lds + p * QBUF + 16384;   // B[kt+2] -> same-parity buffer

        bf16x8 af[4][2], bf[3][2];

        // ---- ph1: read af(mh0: 8) + bf(ni0,1: 4); stage A1[kt+1] ----
#pragma unroll
        for (int mi = 0; mi < 4; ++mi)
#pragma unroll
            for (int ks = 0; ks < 2; ++ks)
                af[mi][ks] = fragr(A0r, wm * 64 + mi * 16 + lr, ks * 4 + lg);
#pragma unroll
        for (int ni = 0; ni < 2; ++ni)
#pragma unroll
            for (int ks = 0; ks < 2; ++ks)
                bf[ni][ks] = fragr(Br, brow0 + ni * 16 + lr, ks * 4 + lg);
        if (kt + 1 < NT) stage_A(A, kt + 1, 1, A1n, t);
        BAR();
        __builtin_amdgcn_s_setprio(1);
#pragma unroll
        for (int mi = 0; mi < 4; ++mi)
#pragma unroll
            for (int ni = 0; ni < 2; ++ni)
#pragma unroll
                for (int ks = 0; ks < 2; ++ks)
                    acc[mi][ni] = __builtin_amdgcn_mfma_f32_16x16x32_bf16(af[mi][ks], bf[ni][ks], acc[mi][ni], 0, 0, 0);
        __builtin_amdgcn_s_setprio(0);
        BAR();

        // ---- ph2: read bf(ni2: 2); stage A0[kt+2] (A0 dead after ph1) ----
#pragma unroll
        for (int ks = 0; ks < 2; ++ks)
            bf[2][ks] = fragr(Br, brow0 + 32 + lr, ks * 4 + lg);
        if (kt + 2 < NT) stage_A(A, kt + 2, 0, A0r, t);
        BAR();
        __builtin_amdgcn_s_setprio(1);
#pragma unroll
        for (int mi = 0; mi < 4; ++mi)
#pragma unroll
            for (int ks = 0; ks < 2; ++ks)
                acc[mi][2] = __builtin_amdgcn_mfma_f32_16x16x32_bf16(af[mi][ks], bf[2][ks], acc[mi][2], 0, 0, 0);
        __builtin_amdgcn_s_setprio(0);
        BAR();

        // ---- ph3: read af(mh1: 8); stage B[kt+2] rows 0-127 (B dead) ----
#pragma unroll
        for (int mi = 0; mi < 4; ++mi)
#pragma unroll
            for (int ks = 0; ks < 2; ++ks)
                af[mi][ks] = fragr(A1r, wm * 64 + mi * 16 + lr, ks * 4 + lg);
        if (kt + 2 < NT) stage_B01(B, kt + 2, Bn, t);
        BAR();
        __builtin_amdgcn_s_setprio(1);
#pragma unroll
        for (int mi = 0; mi < 4; ++mi)
#pragma unroll
            for (int ni = 0; ni < 2; ++ni)
#pragma unroll
                for (int ks = 0; ks < 2; ++ks)
                    acc[4 + mi][ni] = __builtin_amdgcn_mfma_f32_16x16x32_bf16(af[mi][ks], bf[ni][ks], acc[4 + mi][ni], 0, 0, 0);
        __builtin_amdgcn_s_setprio(0);
        BAR();

        // ---- ph4: stage B[kt+2] rows 128-191; counted vmcnt(5) ----
        if (kt + 2 < NT) {
            stage_B2(B, kt + 2, Bn, t);
            VMC5();
        } else if (kt + 1 < NT) {
            VMC0();
        }
        BAR();
        __builtin_amdgcn_s_setprio(1);
#pragma unroll
        for (int mi = 0; mi < 4; ++mi)
#pragma unroll
            for (int ks = 0; ks < 2; ++ks)
                acc[4 + mi][2] = __builtin_amdgcn_mfma_f32_16x16x32_bf16(af[mi][ks], bf[2][ks], acc[4 + mi][2], 0, 0, 0);
        __builtin_amdgcn_s_setprio(0);
        BAR();
    }

    // ---- epilogue: LDS-staged coalesced stores (stride 200 u16) ----
    u16* ep = lds;
#pragma unroll
    for (int mi = 0; mi < 8; ++mi) {
#pragma unroll
        for (int ni = 0; ni < 3; ++ni)
#pragma unroll
            for (int v = 0; v < 4; ++v)
                ep[(wm * 16 + lg * 4 + v) * 200 + wn * 48 + ni * 16 + lr] = f2bf(acc[mi][ni][v]);
        BAR();
#pragma unroll
        for (int c = 0; c < 2; ++c) {
            int ch = c * 512 + t;
            if (ch < 768) {
                int srow = ch / 24, col8 = (ch % 24) * 8;
                int grow = mb + (srow >> 4) * 128 + mi * 16 + (srow & 15);
                *(uint4*)(QKV + (size_t)grow * 3072 + nb + col8) =
                    *(const uint4*)(ep + srow * 200 + col8);
            }
        }
        BAR();
    }
}

// ---------------------------------------------------------------------------
// m97-style 128x128 GEMM (output projection), coalesced f32 epilogue (R7).
// ---------------------------------------------------------------------------
__device__ __forceinline__ void gemm_tile_body_f32(
    const u16* __restrict__ A, const u16* __restrict__ B, float* __restrict__ Cp,
    int K, int ldc, int mb, int nb, u16* sh)
{
    u16* As = sh;
    u16* Bs = sh + 128 * 32;

    const int t  = threadIdx.x;
    const int l  = t & 63, w = t >> 6;
    const int wm = w >> 1, wn = w & 1;
    const int lr = l & 15, lg = l >> 4;

    f32x4 acc[4][4];
#pragma unroll
    for (int i = 0; i < 4; ++i)
#pragma unroll
        for (int j = 0; j < 4; ++j) acc[i][j] = f32x4{0.f, 0.f, 0.f, 0.f};

    for (int k0 = 0; k0 < K; k0 += 32) {
        __syncthreads();
#pragma unroll
        for (int i = 0; i < 2; ++i) {
            int chunk = i * 256 + t;
            int row   = chunk >> 2;
            int c8    = (chunk & 3) << 3;
            const u16* ga = A + (size_t)(mb + row) * K + k0 + c8;
            const u16* gb = B + (size_t)(nb + row) * K + k0 + c8;
            u16* la = As + (i * 256 + w * 64) * 8;
            u16* lb = Bs + (i * 256 + w * 64) * 8;
            __builtin_amdgcn_global_load_lds((AS1 unsigned int*)ga, (AS3 unsigned int*)la, 16, 0, 0);
            __builtin_amdgcn_global_load_lds((AS1 unsigned int*)gb, (AS3 unsigned int*)lb, 16, 0, 0);
        }
        __syncthreads();
        bf16x8 af[4], bfr[4];
#pragma unroll
        for (int mi = 0; mi < 4; ++mi)
            af[mi] = *(const bf16x8*)(As + (wm * 64 + mi * 16 + lr) * 32 + lg * 8);
#pragma unroll
        for (int ni = 0; ni < 4; ++ni)
            bfr[ni] = *(const bf16x8*)(Bs + (wn * 64 + ni * 16 + lr) * 32 + lg * 8);
#pragma unroll
        for (int mi = 0; mi < 4; ++mi)
#pragma unroll
            for (int ni = 0; ni < 4; ++ni)
                acc[mi][ni] = __builtin_amdgcn_mfma_f32_16x16x32_bf16(af[mi], bfr[ni], acc[mi][ni], 0, 0, 0);
    }

    __syncthreads();
    float* epf = (float*)sh;
#pragma unroll
    for (int s = 0; s < 8; ++s) {
        int wmS = s >> 2, miS = s & 3;
        if (wm == wmS) {
#pragma unroll
            for (int ni = 0; ni < 4; ++ni)
#pragma unroll
                for (int v = 0; v < 4; ++v)
                    epf[(lg * 4 + v) * 132 + wn * 64 + ni * 16 + lr] = acc[miS][ni][v];
        }
        __syncthreads();
#pragma unroll
        for (int c = 0; c < 2; ++c) {
            int ch = c * 256 + t;
            int srow = ch >> 5, c4 = (ch & 31) << 2;
            *(float4*)(Cp + (size_t)(mb + wmS * 64 + miS * 16 + srow) * ldc + nb + c4) =
                *(const float4*)(epf + srow * 132 + c4);
        }
        __syncthreads();
    }
}

__global__ __launch_bounds__(256, 2) void gemm_out_kernel(
    const u16* __restrict__ A, const u16* __restrict__ B, float* __restrict__ C)
{
    __shared__ __attribute__((aligned(16))) u16 sh[128 * 32 * 2];  // 16 KB
    int bid = (int)blockIdx.x + (int)gridDim.x * (int)blockIdx.y;  // nwg=512
    int wg  = (bid & 7) * 64 + (bid >> 3);
    int mx  = wg >> 3;
    int my  = wg & 7;
    gemm_tile_body_f32(A, B, C, 1024, 1024, mx * 128, my * 128, sh);
}

// ---------------------------------------------------------------------------
// Causal flash attention (swapped-operand MFMA; exact R6 body — proven 98.5).
// ---------------------------------------------------------------------------
#define SEQ  2048
#define PSTR 72
#define NQT  16

__device__ __forceinline__ void attn_qtile(
    const u16* __restrict__ Qg, const u16* __restrict__ Kg, const u16* __restrict__ Vg,
    u16* __restrict__ outp, int b, int h, int qt,
    u16* QP, u16* Ks, u16* Vt)
{
    const int t  = threadIdx.x;
    const int l  = t & 63, w = t >> 6;
    const int lr = l & 15, lg = l >> 4;
    const int q0 = qt * 128;
    const int sr = t >> 3;
    const int sc = (t & 7) << 3;
    const int vswz = sc;

    __syncthreads();
#pragma unroll
    for (int i = 0; i < 4; ++i) {
        int r = sr + i * 32;
        *(uint4*)(QP + r * PSTR + sc) = *(const uint4*)(Qg + (size_t)(q0 + r) * 3072 + sc);
    }
    __syncthreads();
    bf16x8 qf[2][2];
#pragma unroll
    for (int mi = 0; mi < 2; ++mi)
#pragma unroll
        for (int ks = 0; ks < 2; ++ks)
            qf[mi][ks] = *(const bf16x8*)(QP + (w * 32 + mi * 16 + lr) * PSTR + ks * 32 + lg * 8);

    uint4 kpf[2], vpf[2];
#pragma unroll
    for (int i = 0; i < 2; ++i) {
        int r = sr + i * 32;
        kpf[i] = *(const uint4*)(Kg + (size_t)r * 3072 + sc);
        vpf[i] = *(const uint4*)(Vg + (size_t)r * 3072 + sc);
    }

    f32x4 o[4][2];
#pragma unroll
    for (int nd = 0; nd < 4; ++nd)
#pragma unroll
        for (int mi = 0; mi < 2; ++mi) o[nd][mi] = f32x4{0.f, 0.f, 0.f, 0.f};
    float mrow[2]  = { -__builtin_inff(), -__builtin_inff() };
    float mrowL[2] = { -__builtin_inff(), -__builtin_inff() };
    float lrow[2]  = { 0.f, 0.f };

    const int nkt = 2 * qt + 2;
    for (int kt = 0; kt < nkt; ++kt) {
        const int k0 = kt * 64;
        __syncthreads();
#pragma unroll
        for (int i = 0; i < 2; ++i) {
            int r = sr + i * 32;
            *(uint4*)(Ks + r * PSTR + sc) = kpf[i];
            int rs = r ^ vswz;
            union { uint4 q; u16 u[8]; } uv; uv.q = vpf[i];
#pragma unroll
            for (int j = 0; j < 8; ++j)
                Vt[(sc + j) * PSTR + rs] = uv.u[j];
        }
        if (kt + 1 < nkt) {
            const int k0n = k0 + 64;
#pragma unroll
            for (int i = 0; i < 2; ++i) {
                int r = sr + i * 32;
                kpf[i] = *(const uint4*)(Kg + (size_t)(k0n + r) * 3072 + sc);
                vpf[i] = *(const uint4*)(Vg + (size_t)(k0n + r) * 3072 + sc);
            }
        }
        __syncthreads();

        f32x4 s[4][2];
#pragma unroll
        for (int ni = 0; ni < 4; ++ni)
#pragma unroll
            for (int mi = 0; mi < 2; ++mi) s[ni][mi] = f32x4{0.f, 0.f, 0.f, 0.f};
        __builtin_amdgcn_s_setprio(1);
#pragma unroll
        for (int ks = 0; ks < 2; ++ks) {
            bf16x8 kb[4];
#pragma unroll
            for (int ni = 0; ni < 4; ++ni)
                kb[ni] = *(const bf16x8*)(Ks + (ni * 16 + lr) * PSTR + ks * 32 + lg * 8);
#pragma unroll
            for (int ni = 0; ni < 4; ++ni)
#pragma unroll
                for (int mi = 0; mi < 2; ++mi)
                    s[ni][mi] = __builtin_amdgcn_mfma_f32_16x16x32_bf16(kb[ni], qf[mi][ks], s[ni][mi], 0, 0, 0);
        }
        __builtin_amdgcn_s_setprio(0);

#pragma unroll
        for (int mi = 0; mi < 2; ++mi) {
            if ((k0 + 63) > (q0 + w * 32 + mi * 16)) {
                int qpos = q0 + w * 32 + mi * 16 + lr;
#pragma unroll
                for (int ni = 0; ni < 4; ++ni) {
                    int kb0 = k0 + ni * 16 + lg * 4;
#pragma unroll
                    for (int v = 0; v < 4; ++v)
                        if (kb0 + v > qpos) s[ni][mi][v] = -__builtin_inff();
                }
            }
        }

        float rmax[2];
        bool grew = false;
#pragma unroll
        for (int mi = 0; mi < 2; ++mi) {
            float r = fmaxf(fmaxf(vmax4(s[0][mi]), vmax4(s[1][mi])),
                            fmaxf(vmax4(s[2][mi]), vmax4(s[3][mi])));
            r = fmaxf(r, __shfl_xor(r, 16));
            r = fmaxf(r, __shfl_xor(r, 32));
            rmax[mi] = r;
            grew |= (r > mrow[mi]);
        }
        if (__ballot(grew)) {
#pragma unroll
            for (int mi = 0; mi < 2; ++mi) {
                float mn  = fmaxf(mrow[mi], rmax[mi]);
                float mnL = mn * LOG2E;
                float al  = __builtin_amdgcn_exp2f(mrowL[mi] - mnL);
                mrow[mi]  = mn;
                mrowL[mi] = mnL;
                lrow[mi] *= al;
#pragma unroll
                for (int nd = 0; nd < 4; ++nd)
#pragma unroll
                    for (int v = 0; v < 4; ++v) o[nd][mi][v] *= al;
            }
        }
#pragma unroll
        for (int mi = 0; mi < 2; ++mi) {
            float nmL = -mrowL[mi];
#pragma unroll
            for (int ni = 0; ni < 4; ++ni)
#pragma unroll
                for (int v = 0; v < 4; ++v)
                    s[ni][mi][v] = __builtin_amdgcn_exp2f(
                        __builtin_fmaf(s[ni][mi][v], LOG2E, nmL));
            float sum = (vsum4(s[0][mi]) + vsum4(s[1][mi]))
                      + (vsum4(s[2][mi]) + vsum4(s[3][mi]));
            sum += __shfl_xor(sum, 16);
            sum += __shfl_xor(sum, 32);
            lrow[mi] += sum;
            int prow = (w * 32 + mi * 16 + lr) * PSTR + lg * 4;
#pragma unroll
            for (int ni = 0; ni < 4; ++ni) {
                ushort4 u;
                u.x = f2bf(s[ni][mi][0]); u.y = f2bf(s[ni][mi][1]);
                u.z = f2bf(s[ni][mi][2]); u.w = f2bf(s[ni][mi][3]);
                *(ushort4*)(QP + prow + ni * 16) = u;
            }
        }

        __builtin_amdgcn_s_setprio(1);
#pragma unroll
        for (int ks = 0; ks < 2; ++ks) {
            bf16x8 pa[2], vb[4];
#pragma unroll
            for (int mi = 0; mi < 2; ++mi)
                pa[mi] = *(const bf16x8*)(QP + (w * 32 + mi * 16 + lr) * PSTR + ks * 32 + lg * 8);
#pragma unroll
            for (int nd = 0; nd < 4; ++nd) {
                int d = nd * 16 + lr;
                vb[nd] = *(const bf16x8*)(Vt + d * PSTR + ((ks * 32 + lg * 8) ^ (((d >> 3) & 7) << 3)));
            }
#pragma unroll
            for (int nd = 0; nd < 4; ++nd)
#pragma unroll
                for (int mi = 0; mi < 2; ++mi)
                    o[nd][mi] = __builtin_amdgcn_mfma_f32_16x16x32_bf16(vb[nd], pa[mi], o[nd][mi], 0, 0, 0);
        }
        __builtin_amdgcn_s_setprio(0);
    }

#pragma unroll
    for (int mi = 0; mi < 2; ++mi) {
        float inv = 1.f / lrow[mi];
        int row = q0 + w * 32 + mi * 16 + lr;
        u16* op = outp + (size_t)(b * SEQ + row) * 1024 + h * 64 + lg * 4;
#pragma unroll
        for (int nd = 0; nd < 4; ++nd) {
            ushort4 u;
            u.x = f2bf(o[nd][mi][0] * inv); u.y = f2bf(o[nd][mi][1] * inv);
            u.z = f2bf(o[nd][mi][2] * inv); u.w = f2bf(o[nd][mi][3] * inv);
            *(ushort4*)(op + nd * 16) = u;
        }
    }
}

__global__ __launch_bounds__(256, 2) void attn_kernel(
    const u16* __restrict__ qkv, u16* __restrict__ outp)
{
    __shared__ __attribute__((aligned(16))) u16 QP[128 * PSTR];
    __shared__ __attribute__((aligned(16))) u16 Ks[64 * PSTR];
    __shared__ __attribute__((aligned(16))) u16 Vt[64 * PSTR];

    const int bid = (int)blockIdx.x + (int)blockIdx.y * 8;
    const int xcd = bid & 7;
    const int j   = bid >> 3;
    const int bh  = xcd * 8 + (j & 7);
    const int qp  = j >> 3;
    const int b   = bh >> 4, h = bh & 15;

    const u16* Qg = qkv + (size_t)b * SEQ * 3072 + h * 64;
    const u16* Kg = Qg + 1024;
    const u16* Vg = Qg + 2048;

    attn_qtile(Qg, Kg, Vg, outp, b, h, qp,           QP, Ks, Vt);
    attn_qtile(Qg, Kg, Vg, outp, b, h, NQT - 1 - qp, QP, Ks, Vt);
}

// ---------------------------------------------------------------------------
extern "C" void kernel_launch(void* const* d_in, const int* in_sizes, int n_in,
                              void* d_out, int out_size, void* d_ws, size_t ws_size,
                              hipStream_t stream)
{
    (void)in_sizes; (void)n_in; (void)out_size; (void)ws_size;
    const float* x  = (const float*)d_in[0];
    const float* Wq = (const float*)d_in[1];
    const float* Wk = (const float*)d_in[2];
    const float* Wv = (const float*)d_in[3];
    const float* Wo = (const float*)d_in[4];

    u16*   qkv = (u16*)d_ws;                     // [8192,3072] bf16
    u16*   xb  = qkv + (size_t)8192 * 3072;      // [8192,1024] bf16
    u16*   att = xb;                             // alias: xb dead after QKV GEMM
    u16*   w3  = (u16*)d_out;                    // Wq|Wk|Wv bf16 scratch
    u16*   wob = qkv;                            // Wo bf16 -> dead qkv region
    float* out = (float*)d_out;                  // final [8192,1024] fp32

    cvt_kernel <<<dim3(4096), 256, 0, stream>>>(x, xb, 1048576);
    cvt3_kernel<<<dim3(1536), 256, 0, stream>>>(Wq, Wk, Wv, w3);  // Wq pre-scaled 1/8

    gemm_qkv_256<<<dim3(512), 512, 0, stream>>>(xb, w3, qkv);
    attn_kernel <<<dim3(8, 64), 256, 0, stream>>>(qkv, att);

    cvt_kernel<<<dim3(512), 256, 0, stream>>>(Wo, wob, 131072);
    gemm_out_kernel<<<dim3(64, 8), 256, 0, stream>>>(att, wob, out);
}

// Round 9
// 249.687 us; speedup vs baseline: 1.1447x; 1.0914x over previous
//
#include <hip/hip_runtime.h>
#include <stdint.h>

typedef unsigned short u16;
typedef __attribute__((ext_vector_type(8))) __bf16 bf16x8;
typedef __attribute__((ext_vector_type(4))) float f32x4;

#define AS1 __attribute__((address_space(1)))
#define AS3 __attribute__((address_space(3)))
#define LOG2E 1.4426950408889634f

__device__ __forceinline__ u16 f2bf(float f) {
    union { __bf16 h; u16 u; } cv;
    cv.h = (__bf16)f;   // native cvt (RTNE)
    return cv.u;
}

__device__ __forceinline__ float vmax4(f32x4 x) {
    return fmaxf(fmaxf(x[0], x[1]), fmaxf(x[2], x[3]));
}
__device__ __forceinline__ float vsum4(f32x4 x) {
    return (x[0] + x[1]) + (x[2] + x[3]);
}

// ---------------------------------------------------------------------------
// Merged fp32->bf16 convert: x (8.4M elems) + Wq(1/8)|Wk|Wv. 8 elems/thread.
// ---------------------------------------------------------------------------
__global__ __launch_bounds__(256) void cvt_all(
    const float* __restrict__ x,  const float* __restrict__ wq,
    const float* __restrict__ wk, const float* __restrict__ wv,
    u16* __restrict__ xb, u16* __restrict__ w3)
{
    int i = blockIdx.x * 256 + threadIdx.x;     // 0 .. 1441791
    const float* s; u16* d; float sc = 1.0f; int j;
    if (i < 1048576) {
        s = x; d = xb; j = i;
    } else {
        int k = i - 1048576;
        int seg = k >> 17;
        j = k & 131071;
        s = (seg == 0) ? wq : (seg == 1) ? wk : wv;
        sc = (seg == 0) ? 0.125f : 1.0f;
        d = w3 + ((size_t)seg << 20);
    }
    const float4* sp = (const float4*)s;
    float4 f0 = sp[(size_t)j * 2], f1 = sp[(size_t)j * 2 + 1];
    ushort4 a, b;
    a.x = f2bf(f0.x * sc); a.y = f2bf(f0.y * sc); a.z = f2bf(f0.z * sc); a.w = f2bf(f0.w * sc);
    b.x = f2bf(f1.x * sc); b.y = f2bf(f1.y * sc); b.z = f2bf(f1.z * sc); b.w = f2bf(f1.w * sc);
    ((ushort4*)d)[(size_t)j * 2]     = a;
    ((ushort4*)d)[(size_t)j * 2 + 1] = b;
}

// plain cvt for Wo (must run after attn: dst aliases the dead qkv region)
__global__ __launch_bounds__(256) void cvt_kernel(
    const float* __restrict__ src, u16* __restrict__ dst, int n8)
{
    int i = blockIdx.x * 256 + threadIdx.x;
    if (i >= n8) return;
    const float4* s = (const float4*)src;
    float4 f0 = s[(size_t)i * 2], f1 = s[(size_t)i * 2 + 1];
    ushort4 a, b;
    a.x = f2bf(f0.x); a.y = f2bf(f0.y); a.z = f2bf(f0.z); a.w = f2bf(f0.w);
    b.x = f2bf(f1.x); b.y = f2bf(f1.y); b.z = f2bf(f1.z); b.w = f2bf(f1.w);
    ((ushort4*)dst)[(size_t)i * 2]     = a;
    ((ushort4*)dst)[(size_t)i * 2 + 1] = b;
}

// ---------------------------------------------------------------------------
// QKV GEMM: 256x192 / BK=64, minimum 2-phase (T3 catalog recipe):
// per K-tile: {stage kt+1 -> other buf; ds_read all frags; MFMA; syncthreads}.
// 512 thr (8 waves 2Mx4N, per-wave 128x48); LDS 112 KB 2-dbuf; G4 swizzle
// byte^=(row&7)<<4 both sides; grid 512 = 2 clean rounds on 256 CUs.
// ---------------------------------------------------------------------------
#define QBUF 28672   // u16 per buffer: A0 8192 | A1 8192 | B 12288

__device__ __forceinline__ void stage_A(
    const u16* __restrict__ G, int kt, int hm, u16* region, int t)
{
    int w6 = t & ~63;
#pragma unroll
    for (int i = 0; i < 2; ++i) {
        int s = i * 512 + t;
        int r = s >> 3;
        int j = (s & 7) ^ (r & 7);
        int row = (r & 63) + ((r >> 6) << 7) + (hm << 6);   // mh-interleaved
        const u16* g = G + (size_t)row * 1024 + kt * 64 + j * 8;
        u16* lp = region + (i * 512 + w6) * 8;              // wave-uniform base
        __builtin_amdgcn_global_load_lds((AS1 unsigned int*)g, (AS3 unsigned int*)lp, 16, 0, 0);
    }
}

__device__ __forceinline__ void stage_B01(
    const u16* __restrict__ G, int kt, u16* region, int t)
{
    int w6 = t & ~63;
#pragma unroll
    for (int i = 0; i < 2; ++i) {
        int s = i * 512 + t;
        int r = s >> 3;
        int j = (s & 7) ^ (r & 7);
        const u16* g = G + (size_t)r * 1024 + kt * 64 + j * 8;
        u16* lp = region + (i * 512 + w6) * 8;
        __builtin_amdgcn_global_load_lds((AS1 unsigned int*)g, (AS3 unsigned int*)lp, 16, 0, 0);
    }
}

__device__ __forceinline__ void stage_B2(
    const u16* __restrict__ G, int kt, u16* region, int t)
{
    int r = t >> 3;
    int j = (t & 7) ^ (r & 7);
    const u16* g = G + (size_t)(128 + r) * 1024 + kt * 64 + j * 8;
    u16* lp = region + 8192 + ((t & ~63)) * 8;
    __builtin_amdgcn_global_load_lds((AS1 unsigned int*)g, (AS3 unsigned int*)lp, 16, 0, 0);
}

__device__ __forceinline__ bf16x8 fragr(const u16* region, int row, int j) {
    int byte = row * 128 + ((j ^ (row & 7)) << 4);
    return *(const bf16x8*)((const char*)region + byte);
}

__global__ __launch_bounds__(512, 2) void gemm_qkv_2ph(
    const u16* __restrict__ X, const u16* __restrict__ W3, u16* __restrict__ QKV)
{
    __shared__ __attribute__((aligned(16))) u16 lds[57344];   // 112 KB

    const int t  = threadIdx.x;
    const int l  = t & 63, w = t >> 6;
    const int wm = w >> 2, wn = w & 3;
    const int lr = l & 15, lg = l >> 4;

    // bijective XCD chunking: nwg=512=8*64
    int bid = (int)blockIdx.x;
    int wg  = (bid & 7) * 64 + (bid >> 3);
    int mx  = wg >> 4, ny = wg & 15;
    const int mb = mx * 256, nb = ny * 192;
    const u16* A = X  + (size_t)mb * 1024;
    const u16* B = W3 + (size_t)nb * 1024;

    const int NT = 16;   // K=1024 / BK=64

    // prologue: stage tile 0 into buf0, drain, barrier
    stage_A  (A, 0, 0, lds + 0,     t);
    stage_A  (A, 0, 1, lds + 8192,  t);
    stage_B01(B, 0,    lds + 16384, t);
    stage_B2 (B, 0,    lds + 16384, t);
    __syncthreads();

    f32x4 acc[8][3];
#pragma unroll
    for (int i = 0; i < 8; ++i)
#pragma unroll
        for (int j = 0; j < 3; ++j) acc[i][j] = f32x4{0.f, 0.f, 0.f, 0.f};

    const int brow0 = wn * 48;

    for (int kt = 0; kt < NT; ++kt) {
        const int p = kt & 1;
        u16* cur = lds + p * QBUF;
        u16* nxt = lds + (p ^ 1) * QBUF;

        // ---- issue next tile's stage first (overlaps this tile's compute) ----
        if (kt + 1 < NT) {
            stage_A  (A, kt + 1, 0, nxt,         t);
            stage_A  (A, kt + 1, 1, nxt + 8192,  t);
            stage_B01(B, kt + 1,    nxt + 16384, t);
            stage_B2 (B, kt + 1,    nxt + 16384, t);
        }

        // ---- ds_read frags + MFMA (compiler schedules waits) ----
        bf16x8 bf[3][2], af[4][2];
#pragma unroll
        for (int ni = 0; ni < 3; ++ni)
#pragma unroll
            for (int ks = 0; ks < 2; ++ks)
                bf[ni][ks] = fragr(cur + 16384, brow0 + ni * 16 + lr, ks * 4 + lg);
#pragma unroll
        for (int mi = 0; mi < 4; ++mi)
#pragma unroll
            for (int ks = 0; ks < 2; ++ks)
                af[mi][ks] = fragr(cur, wm * 64 + mi * 16 + lr, ks * 4 + lg);
        __builtin_amdgcn_s_setprio(1);
#pragma unroll
        for (int mi = 0; mi < 4; ++mi)
#pragma unroll
            for (int ni = 0; ni < 3; ++ni)
#pragma unroll
                for (int ks = 0; ks < 2; ++ks)
                    acc[mi][ni] = __builtin_amdgcn_mfma_f32_16x16x32_bf16(af[mi][ks], bf[ni][ks], acc[mi][ni], 0, 0, 0);
        __builtin_amdgcn_s_setprio(0);
#pragma unroll
        for (int mi = 0; mi < 4; ++mi)
#pragma unroll
            for (int ks = 0; ks < 2; ++ks)
                af[mi][ks] = fragr(cur + 8192, wm * 64 + mi * 16 + lr, ks * 4 + lg);
        __builtin_amdgcn_s_setprio(1);
#pragma unroll
        for (int mi = 0; mi < 4; ++mi)
#pragma unroll
            for (int ni = 0; ni < 3; ++ni)
#pragma unroll
                for (int ks = 0; ks < 2; ++ks)
                    acc[4 + mi][ni] = __builtin_amdgcn_mfma_f32_16x16x32_bf16(af[mi][ks], bf[ni][ks], acc[4 + mi][ni], 0, 0, 0);
        __builtin_amdgcn_s_setprio(0);

        __syncthreads();   // drains stage (vmcnt0) + reads; next tile ready
    }

    // ---- epilogue: LDS-staged coalesced stores (stride 200 u16) ----
    u16* ep = lds;
#pragma unroll
    for (int mi = 0; mi < 8; ++mi) {
#pragma unroll
        for (int ni = 0; ni < 3; ++ni)
#pragma unroll
            for (int v = 0; v < 4; ++v)
                ep[(wm * 16 + lg * 4 + v) * 200 + wn * 48 + ni * 16 + lr] = f2bf(acc[mi][ni][v]);
        __syncthreads();
#pragma unroll
        for (int c = 0; c < 2; ++c) {
            int ch = c * 512 + t;
            if (ch < 768) {
                int srow = ch / 24, col8 = (ch % 24) * 8;
                int grow = mb + (srow >> 4) * 128 + mi * 16 + (srow & 15);
                *(uint4*)(QKV + (size_t)grow * 3072 + nb + col8) =
                    *(const uint4*)(ep + srow * 200 + col8);
            }
        }
        __syncthreads();
    }
}

// ---------------------------------------------------------------------------
// Output GEMM: 128x128 / BK=64 minimum 2-phase; 64 KB LDS -> 2 blocks/CU;
// grid 512 = one full concurrent round. Coalesced f32 epilogue.
// ---------------------------------------------------------------------------
__device__ __forceinline__ void stage_128(
    const u16* __restrict__ G, int kt, u16* region, int t)
{
    int w6 = t & ~63;
#pragma unroll
    for (int i = 0; i < 4; ++i) {
        int s = i * 256 + t;
        int r = s >> 3;
        int j = (s & 7) ^ (r & 7);
        const u16* g = G + (size_t)r * 1024 + kt * 64 + j * 8;
        u16* lp = region + (i * 256 + w6) * 8;
        __builtin_amdgcn_global_load_lds((AS1 unsigned int*)g, (AS3 unsigned int*)lp, 16, 0, 0);
    }
}

__global__ __launch_bounds__(256, 2) void gemm_out_2ph(
    const u16* __restrict__ Ag, const u16* __restrict__ Bg, float* __restrict__ C)
{
    __shared__ __attribute__((aligned(16))) u16 lds[32768];   // 64 KB

    const int t  = threadIdx.x;
    const int l  = t & 63, w = t >> 6;
    const int wm = w >> 1, wn = w & 1;
    const int lr = l & 15, lg = l >> 4;

    int bid = (int)blockIdx.x;                  // nwg=512=8*64
    int wg  = (bid & 7) * 64 + (bid >> 3);
    int mx  = wg >> 3, my = wg & 7;
    const int mb = mx * 128, nb = my * 128;
    const u16* A = Ag + (size_t)mb * 1024;
    const u16* B = Bg + (size_t)nb * 1024;

    const int NT = 16;

    stage_128(A, 0, lds + 0,    t);
    stage_128(B, 0, lds + 8192, t);
    __syncthreads();

    f32x4 acc[4][4];
#pragma unroll
    for (int i = 0; i < 4; ++i)
#pragma unroll
        for (int j = 0; j < 4; ++j) acc[i][j] = f32x4{0.f, 0.f, 0.f, 0.f};

    for (int kt = 0; kt < NT; ++kt) {
        const int p = kt & 1;
        u16* cur = lds + p * 16384;
        u16* nxt = lds + (p ^ 1) * 16384;

        if (kt + 1 < NT) {
            stage_128(A, kt + 1, nxt,        t);
            stage_128(B, kt + 1, nxt + 8192, t);
        }

        bf16x8 af[4][2], bf[4][2];
#pragma unroll
        for (int mi = 0; mi < 4; ++mi)
#pragma unroll
            for (int ks = 0; ks < 2; ++ks)
                af[mi][ks] = fragr(cur, wm * 64 + mi * 16 + lr, ks * 4 + lg);
#pragma unroll
        for (int ni = 0; ni < 4; ++ni)
#pragma unroll
            for (int ks = 0; ks < 2; ++ks)
                bf[ni][ks] = fragr(cur + 8192, wn * 64 + ni * 16 + lr, ks * 4 + lg);
        __builtin_amdgcn_s_setprio(1);
#pragma unroll
        for (int mi = 0; mi < 4; ++mi)
#pragma unroll
            for (int ni = 0; ni < 4; ++ni)
#pragma unroll
                for (int ks = 0; ks < 2; ++ks)
                    acc[mi][ni] = __builtin_amdgcn_mfma_f32_16x16x32_bf16(af[mi][ks], bf[ni][ks], acc[mi][ni], 0, 0, 0);
        __builtin_amdgcn_s_setprio(0);

        __syncthreads();
    }

    // ---- epilogue: LDS-staged float4 stores (stride 132 f32) ----
    float* epf = (float*)lds;
#pragma unroll
    for (int s = 0; s < 8; ++s) {
        int wmS = s >> 2, miS = s & 3;
        if (wm == wmS) {
#pragma unroll
            for (int ni = 0; ni < 4; ++ni)
#pragma unroll
                for (int v = 0; v < 4; ++v)
                    epf[(lg * 4 + v) * 132 + wn * 64 + ni * 16 + lr] = acc[miS][ni][v];
        }
        __syncthreads();
#pragma unroll
        for (int c = 0; c < 2; ++c) {
            int ch = c * 256 + t;
            int srow = ch >> 5, c4 = (ch & 31) << 2;
            *(float4*)(C + (size_t)(mb + wmS * 64 + miS * 16 + srow) * 1024 + nb + c4) =
                *(const float4*)(epf + srow * 132 + c4);
        }
        __syncthreads();
    }
}

// ---------------------------------------------------------------------------
// Causal flash attention (swapped-operand MFMA; proven R6 body, 98.5 us).
// ---------------------------------------------------------------------------
#define SEQ  2048
#define PSTR 72
#define NQT  16

__device__ __forceinline__ void attn_qtile(
    const u16* __restrict__ Qg, const u16* __restrict__ Kg, const u16* __restrict__ Vg,
    u16* __restrict__ outp, int b, int h, int qt,
    u16* QP, u16* Ks, u16* Vt)
{
    const int t  = threadIdx.x;
    const int l  = t & 63, w = t >> 6;
    const int lr = l & 15, lg = l >> 4;
    const int q0 = qt * 128;
    const int sr = t >> 3;
    const int sc = (t & 7) << 3;
    const int vswz = sc;

    __syncthreads();
#pragma unroll
    for (int i = 0; i < 4; ++i) {
        int r = sr + i * 32;
        *(uint4*)(QP + r * PSTR + sc) = *(const uint4*)(Qg + (size_t)(q0 + r) * 3072 + sc);
    }
    __syncthreads();
    bf16x8 qf[2][2];
#pragma unroll
    for (int mi = 0; mi < 2; ++mi)
#pragma unroll
        for (int ks = 0; ks < 2; ++ks)
            qf[mi][ks] = *(const bf16x8*)(QP + (w * 32 + mi * 16 + lr) * PSTR + ks * 32 + lg * 8);

    uint4 kpf[2], vpf[2];
#pragma unroll
    for (int i = 0; i < 2; ++i) {
        int r = sr + i * 32;
        kpf[i] = *(const uint4*)(Kg + (size_t)r * 3072 + sc);
        vpf[i] = *(const uint4*)(Vg + (size_t)r * 3072 + sc);
    }

    f32x4 o[4][2];
#pragma unroll
    for (int nd = 0; nd < 4; ++nd)
#pragma unroll
        for (int mi = 0; mi < 2; ++mi) o[nd][mi] = f32x4{0.f, 0.f, 0.f, 0.f};
    float mrow[2]  = { -__builtin_inff(), -__builtin_inff() };
    float mrowL[2] = { -__builtin_inff(), -__builtin_inff() };
    float lrow[2]  = { 0.f, 0.f };

    const int nkt = 2 * qt + 2;
    for (int kt = 0; kt < nkt; ++kt) {
        const int k0 = kt * 64;
        __syncthreads();
#pragma unroll
        for (int i = 0; i < 2; ++i) {
            int r = sr + i * 32;
            *(uint4*)(Ks + r * PSTR + sc) = kpf[i];
            int rs = r ^ vswz;
            union { uint4 q; u16 u[8]; } uv; uv.q = vpf[i];
#pragma unroll
            for (int j = 0; j < 8; ++j)
                Vt[(sc + j) * PSTR + rs] = uv.u[j];
        }
        if (kt + 1 < nkt) {
            const int k0n = k0 + 64;
#pragma unroll
            for (int i = 0; i < 2; ++i) {
                int r = sr + i * 32;
                kpf[i] = *(const uint4*)(Kg + (size_t)(k0n + r) * 3072 + sc);
                vpf[i] = *(const uint4*)(Vg + (size_t)(k0n + r) * 3072 + sc);
            }
        }
        __syncthreads();

        f32x4 s[4][2];
#pragma unroll
        for (int ni = 0; ni < 4; ++ni)
#pragma unroll
            for (int mi = 0; mi < 2; ++mi) s[ni][mi] = f32x4{0.f, 0.f, 0.f, 0.f};
        __builtin_amdgcn_s_setprio(1);
#pragma unroll
        for (int ks = 0; ks < 2; ++ks) {
            bf16x8 kb[4];
#pragma unroll
            for (int ni = 0; ni < 4; ++ni)
                kb[ni] = *(const bf16x8*)(Ks + (ni * 16 + lr) * PSTR + ks * 32 + lg * 8);
#pragma unroll
            for (int ni = 0; ni < 4; ++ni)
#pragma unroll
                for (int mi = 0; mi < 2; ++mi)
                    s[ni][mi] = __builtin_amdgcn_mfma_f32_16x16x32_bf16(kb[ni], qf[mi][ks], s[ni][mi], 0, 0, 0);
        }
        __builtin_amdgcn_s_setprio(0);

#pragma unroll
        for (int mi = 0; mi < 2; ++mi) {
            if ((k0 + 63) > (q0 + w * 32 + mi * 16)) {
                int qpos = q0 + w * 32 + mi * 16 + lr;
#pragma unroll
                for (int ni = 0; ni < 4; ++ni) {
                    int kb0 = k0 + ni * 16 + lg * 4;
#pragma unroll
                    for (int v = 0; v < 4; ++v)
                        if (kb0 + v > qpos) s[ni][mi][v] = -__builtin_inff();
                }
            }
        }

        float rmax[2];
        bool grew = false;
#pragma unroll
        for (int mi = 0; mi < 2; ++mi) {
            float r = fmaxf(fmaxf(vmax4(s[0][mi]), vmax4(s[1][mi])),
                            fmaxf(vmax4(s[2][mi]), vmax4(s[3][mi])));
            r = fmaxf(r, __shfl_xor(r, 16));
            r = fmaxf(r, __shfl_xor(r, 32));
            rmax[mi] = r;
            grew |= (r > mrow[mi]);
        }
        if (__ballot(grew)) {
#pragma unroll
            for (int mi = 0; mi < 2; ++mi) {
                float mn  = fmaxf(mrow[mi], rmax[mi]);
                float mnL = mn * LOG2E;
                float al  = __builtin_amdgcn_exp2f(mrowL[mi] - mnL);
                mrow[mi]  = mn;
                mrowL[mi] = mnL;
                lrow[mi] *= al;
#pragma unroll
                for (int nd = 0; nd < 4; ++nd)
#pragma unroll
                    for (int v = 0; v < 4; ++v) o[nd][mi][v] *= al;
            }
        }
#pragma unroll
        for (int mi = 0; mi < 2; ++mi) {
            float nmL = -mrowL[mi];
#pragma unroll
            for (int ni = 0; ni < 4; ++ni)
#pragma unroll
                for (int v = 0; v < 4; ++v)
                    s[ni][mi][v] = __builtin_amdgcn_exp2f(
                        __builtin_fmaf(s[ni][mi][v], LOG2E, nmL));
            float sum = (vsum4(s[0][mi]) + vsum4(s[1][mi]))
                      + (vsum4(s[2][mi]) + vsum4(s[3][mi]));
            sum += __shfl_xor(sum, 16);
            sum += __shfl_xor(sum, 32);
            lrow[mi] += sum;
            int prow = (w * 32 + mi * 16 + lr) * PSTR + lg * 4;
#pragma unroll
            for (int ni = 0; ni < 4; ++ni) {
                ushort4 u;
                u.x = f2bf(s[ni][mi][0]); u.y = f2bf(s[ni][mi][1]);
                u.z = f2bf(s[ni][mi][2]); u.w = f2bf(s[ni][mi][3]);
                *(ushort4*)(QP + prow + ni * 16) = u;
            }
        }

        __builtin_amdgcn_s_setprio(1);
#pragma unroll
        for (int ks = 0; ks < 2; ++ks) {
            bf16x8 pa[2], vb[4];
#pragma unroll
            for (int mi = 0; mi < 2; ++mi)
                pa[mi] = *(const bf16x8*)(QP + (w * 32 + mi * 16 + lr) * PSTR + ks * 32 + lg * 8);
#pragma unroll
            for (int nd = 0; nd < 4; ++nd) {
                int d = nd * 16 + lr;
                vb[nd] = *(const bf16x8*)(Vt + d * PSTR + ((ks * 32 + lg * 8) ^ (((d >> 3) & 7) << 3)));
            }
#pragma unroll
            for (int nd = 0; nd < 4; ++nd)
#pragma unroll
                for (int mi = 0; mi < 2; ++mi)
                    o[nd][mi] = __builtin_amdgcn_mfma_f32_16x16x32_bf16(vb[nd], pa[mi], o[nd][mi], 0, 0, 0);
        }
        __builtin_amdgcn_s_setprio(0);
    }

#pragma unroll
    for (int mi = 0; mi < 2; ++mi) {
        float inv = 1.f / lrow[mi];
        int row = q0 + w * 32 + mi * 16 + lr;
        u16* op = outp + (size_t)(b * SEQ + row) * 1024 + h * 64 + lg * 4;
#pragma unroll
        for (int nd = 0; nd < 4; ++nd) {
            ushort4 u;
            u.x = f2bf(o[nd][mi][0] * inv); u.y = f2bf(o[nd][mi][1] * inv);
            u.z = f2bf(o[nd][mi][2] * inv); u.w = f2bf(o[nd][mi][3] * inv);
            *(ushort4*)(op + nd * 16) = u;
        }
    }
}

__global__ __launch_bounds__(256, 2) void attn_kernel(
    const u16* __restrict__ qkv, u16* __restrict__ outp)
{
    __shared__ __attribute__((aligned(16))) u16 QP[128 * PSTR];
    __shared__ __attribute__((aligned(16))) u16 Ks[64 * PSTR];
    __shared__ __attribute__((aligned(16))) u16 Vt[64 * PSTR];

    const int bid = (int)blockIdx.x + (int)blockIdx.y * 8;
    const int xcd = bid & 7;
    const int j   = bid >> 3;
    const int bh  = xcd * 8 + (j & 7);
    const int qp  = j >> 3;
    const int b   = bh >> 4, h = bh & 15;

    const u16* Qg = qkv + (size_t)b * SEQ * 3072 + h * 64;
    const u16* Kg = Qg + 1024;
    const u16* Vg = Qg + 2048;

    attn_qtile(Qg, Kg, Vg, outp, b, h, qp,           QP, Ks, Vt);
    attn_qtile(Qg, Kg, Vg, outp, b, h, NQT - 1 - qp, QP, Ks, Vt);
}

// ---------------------------------------------------------------------------
extern "C" void kernel_launch(void* const* d_in, const int* in_sizes, int n_in,
                              void* d_out, int out_size, void* d_ws, size_t ws_size,
                              hipStream_t stream)
{
    (void)in_sizes; (void)n_in; (void)out_size; (void)ws_size;
    const float* x  = (const float*)d_in[0];
    const float* Wq = (const float*)d_in[1];
    const float* Wk = (const float*)d_in[2];
    const float* Wv = (const float*)d_in[3];
    const float* Wo = (const float*)d_in[4];

    u16*   qkv = (u16*)d_ws;                     // [8192,3072] bf16
    u16*   xb  = qkv + (size_t)8192 * 3072;      // [8192,1024] bf16
    u16*   att = xb;                             // alias: xb dead after QKV GEMM
    u16*   w3  = (u16*)d_out;                    // Wq|Wk|Wv bf16 scratch
    u16*   wob = qkv;                            // Wo bf16 -> dead qkv region
    float* out = (float*)d_out;                  // final [8192,1024] fp32

    cvt_all<<<dim3(5632), 256, 0, stream>>>(x, Wq, Wk, Wv, xb, w3);

    gemm_qkv_2ph<<<dim3(512), 512, 0, stream>>>(xb, w3, qkv);
    attn_kernel <<<dim3(8, 64), 256, 0, stream>>>(qkv, att);

    cvt_kernel<<<dim3(512), 256, 0, stream>>>(Wo, wob, 131072);
    gemm_out_2ph<<<dim3(512), 256, 0, stream>>>(att, wob, out);
}